// Round 8
// baseline (426.708 us; speedup 1.0000x reference)
//
#include <hip/hip_runtime.h>
#include <hip/hip_bf16.h>
#include <math.h>

// ===========================================================================
// f64-accumulate / f32-storage-grid pipeline (R2/R3 numerics, proven).
// R7: GEMM1/GEMM2 use v_mfma_f64_16x16x4 (same 78.6 TF peak as the f64
// vector pipe, but 1 instr / 2048 FLOP -> issue-bound ceiling lifted).
// k order: quads of 4 inside MFMA, quads ascending, chunks ascending.
// ===========================================================================

typedef double f64x4 __attribute__((ext_vector_type(4)));

// ---------------------------------------------------------------------------
// conv1: conv(1->8,3x3,SAME) + bias + relu + maxpool2 -> feat1 [1024,8,32,32]
// ---------------------------------------------------------------------------
__global__ __launch_bounds__(256) void conv1_kernel(
    const float* __restrict__ x, const float* __restrict__ cw1,
    const float* __restrict__ cb1, float* __restrict__ feat1) {
  __shared__ float sX[66 * 66];
  __shared__ float sW1[72];
  __shared__ float sB1[8];

  const int b = blockIdx.x;
  const int t = threadIdx.x;

  for (int i = t; i < 66 * 66; i += 256) sX[i] = 0.0f;
  if (t < 72) sW1[t] = cw1[t];
  if (t < 8)  sB1[t] = cb1[t];
  __syncthreads();

  const float* xb = x + (size_t)b * 4096;
  for (int i = t; i < 4096; i += 256)
    sX[((i >> 6) + 1) * 66 + (i & 63) + 1] = xb[i];
  __syncthreads();

  for (int task = t; task < 2048; task += 256) {
    const int ch = task >> 8;
    const int rem = task & 255;
    const int py = rem >> 3;
    const int px0 = (rem & 7) * 4;

    double w9[9];
#pragma unroll
    for (int k = 0; k < 9; ++k) w9[k] = (double)sW1[ch * 9 + k];

    float reg[4][10];
#pragma unroll
    for (int r = 0; r < 4; ++r)
#pragma unroll
      for (int c = 0; c < 5; ++c) {
        const float2 v =
            *(const float2*)&sX[(2 * py + r) * 66 + 2 * px0 + 2 * c];
        reg[r][2 * c] = v.x;
        reg[r][2 * c + 1] = v.y;
      }

    float out4[4];
#pragma unroll
    for (int px = 0; px < 4; ++px) {
      double best = -1e300;
#pragma unroll
      for (int dy = 0; dy < 2; ++dy) {
#pragma unroll
        for (int dx = 0; dx < 2; ++dx) {
          double s = 0.0;
#pragma unroll
          for (int ky = 0; ky < 3; ++ky)
#pragma unroll
            for (int kx = 0; kx < 3; ++kx)
              s = fma((double)reg[dy + ky][2 * px + dx + kx], w9[ky * 3 + kx],
                      s);
          best = fmax(best, s);
        }
      }
      out4[px] = (float)fmax(best + (double)sB1[ch], 0.0);
    }
    *(float4*)&feat1[(size_t)b * 8192 + ch * 1024 + py * 32 + px0] =
        make_float4(out4[0], out4[1], out4[2], out4[3]);
  }
}

// ---------------------------------------------------------------------------
// conv2 (R5-proven, no spill): conv(8->16)+bias+relu+pool -> flat [1024,4096]
// ---------------------------------------------------------------------------
__global__ __launch_bounds__(256) void conv2_kernel(
    const float* __restrict__ feat1, const float* __restrict__ cw2,
    const float* __restrict__ cb2, float* __restrict__ flat) {
  __shared__ float sF[8 * 34 * 34];
  __shared__ float sW2[1152];
  __shared__ float sB2[16];

  const int b = blockIdx.x;
  const int t = threadIdx.x;

  for (int i = t; i < 8 * 34 * 34; i += 256) sF[i] = 0.0f;
  for (int i = t; i < 1152; i += 256) sW2[i] = cw2[i];
  if (t < 16) sB2[t] = cb2[t];
  __syncthreads();

  const float* fb = feat1 + (size_t)b * 8192;
  for (int i = t; i < 8192; i += 256) {
    const int ch = i >> 10, pos = i & 1023;
    sF[ch * 1156 + ((pos >> 5) + 1) * 34 + (pos & 31) + 1] = fb[i];
  }
  __syncthreads();

  const int py = t >> 4, px = t & 15;
  float* ob = flat + (size_t)b * 4096 + py * 16 + px;

#pragma unroll 1
  for (int oh = 0; oh < 2; ++oh) {
    double acc[8][4];
#pragma unroll
    for (int o = 0; o < 8; ++o)
#pragma unroll
      for (int q = 0; q < 4; ++q) acc[o][q] = 0.0;

#pragma unroll
    for (int ic = 0; ic < 8; ++ic) {
      float r[4][4];
#pragma unroll
      for (int iy = 0; iy < 4; ++iy) {
        const float2 v0 =
            *(const float2*)&sF[ic * 1156 + (2 * py + iy) * 34 + 2 * px];
        const float2 v1 =
            *(const float2*)&sF[ic * 1156 + (2 * py + iy) * 34 + 2 * px + 2];
        r[iy][0] = v0.x; r[iy][1] = v0.y; r[iy][2] = v1.x; r[iy][3] = v1.y;
      }
#pragma unroll
      for (int o = 0; o < 8; ++o) {
        const float* w = &sW2[(oh * 8 + o) * 72 + ic * 9];
        double w9[9];
#pragma unroll
        for (int k = 0; k < 9; ++k) w9[k] = (double)w[k];
#pragma unroll
        for (int dy = 0; dy < 2; ++dy)
#pragma unroll
          for (int dx = 0; dx < 2; ++dx) {
            double s = acc[o][dy * 2 + dx];
#pragma unroll
            for (int ky = 0; ky < 3; ++ky)
#pragma unroll
              for (int kx = 0; kx < 3; ++kx)
                s = fma((double)r[dy + ky][dx + kx], w9[ky * 3 + kx], s);
            acc[o][dy * 2 + dx] = s;
          }
      }
    }
#pragma unroll
    for (int o = 0; o < 8; ++o) {
      const int oc = oh * 8 + o;
      const double best =
          fmax(fmax(acc[o][0], acc[o][1]), fmax(acc[o][2], acc[o][3]));
      ob[oc * 256] = (float)fmax(best + (double)sB2[oc], 0.0);
    }
  }
}

// ---------------------------------------------------------------------------
// Fallback fused conv (R2/R3 kernel) for small-ws path.
// ---------------------------------------------------------------------------
__global__ __launch_bounds__(256) void conv_fused(
    const float* __restrict__ x,
    const float* __restrict__ cw1, const float* __restrict__ cb1,
    const float* __restrict__ cw2, const float* __restrict__ cb2,
    float* __restrict__ flat) {
  __shared__ float sX[66 * 66];
  __shared__ float sF[8 * 34 * 34];
  __shared__ float sW1[72];
  __shared__ float sW2[1152];
  __shared__ float sB1[8];
  __shared__ float sB2[16];

  const int b = blockIdx.x;
  const int t = threadIdx.x;

  for (int i = t; i < 66 * 66; i += 256) sX[i] = 0.0f;
  for (int i = t; i < 8 * 34 * 34; i += 256) sF[i] = 0.0f;
  if (t < 72) sW1[t] = cw1[t];
  for (int i = t; i < 1152; i += 256) sW2[i] = cw2[i];
  if (t < 8)  sB1[t] = cb1[t];
  if (t < 16) sB2[t] = cb2[t];
  __syncthreads();

  const float* xb = x + (size_t)b * 4096;
  for (int i = t; i < 4096; i += 256)
    sX[((i >> 6) + 1) * 66 + (i & 63) + 1] = xb[i];
  __syncthreads();

  for (int p = t; p < 8192; p += 256) {
    const int ch = p >> 10, pos = p & 1023;
    const int py1 = pos >> 5, px1 = pos & 31;
    double best = -1e300;
#pragma unroll
    for (int dy = 0; dy < 2; ++dy)
#pragma unroll
      for (int dx = 0; dx < 2; ++dx) {
        const int y = 2 * py1 + dy, xx = 2 * px1 + dx;
        double s = 0.0;
#pragma unroll
        for (int ky = 0; ky < 3; ++ky)
#pragma unroll
          for (int kx = 0; kx < 3; ++kx)
            s = fma((double)sX[(y + ky) * 66 + xx + kx],
                    (double)sW1[ch * 9 + ky * 3 + kx], s);
        best = fmax(best, s);
      }
    sF[ch * 1156 + (py1 + 1) * 34 + px1 + 1] =
        (float)fmax(best + (double)sB1[ch], 0.0);
  }
  __syncthreads();

  const int py = t >> 4, px = t & 15;
  for (int oh = 0; oh < 2; ++oh) {
    double acc[8][4];
#pragma unroll
    for (int o = 0; o < 8; ++o)
#pragma unroll
      for (int q = 0; q < 4; ++q) acc[o][q] = 0.0;
#pragma unroll
    for (int ic = 0; ic < 8; ++ic) {
      double r[4][4];
#pragma unroll
      for (int iy = 0; iy < 4; ++iy)
#pragma unroll
        for (int ix = 0; ix < 4; ++ix)
          r[iy][ix] = (double)sF[ic * 1156 + (2 * py + iy) * 34 + 2 * px + ix];
#pragma unroll
      for (int o = 0; o < 8; ++o) {
        const float* w = &sW2[(oh * 8 + o) * 72 + ic * 9];
        double w9[9];
#pragma unroll
        for (int k = 0; k < 9; ++k) w9[k] = (double)w[k];
#pragma unroll
        for (int dy = 0; dy < 2; ++dy)
#pragma unroll
          for (int dx = 0; dx < 2; ++dx) {
            double s = acc[o][dy * 2 + dx];
#pragma unroll
            for (int ky = 0; ky < 3; ++ky)
#pragma unroll
              for (int kx = 0; kx < 3; ++kx)
                s = fma(r[dy + ky][dx + kx], w9[ky * 3 + kx], s);
            acc[o][dy * 2 + dx] = s;
          }
      }
    }
    float* ob = flat + (size_t)b * 4096 + py * 16 + px;
#pragma unroll
    for (int o = 0; o < 8; ++o) {
      const int oc = oh * 8 + o;
      double best =
          fmax(fmax(acc[o][0], acc[o][1]), fmax(acc[o][2], acc[o][3]));
      ob[oc * 256] = (float)fmax(best + (double)sB2[oc], 0.0);
    }
  }
}

// ---------------------------------------------------------------------------
// Split-K NT GEMM via v_mfma_f64_16x16x4: block tile 128(M)x64(N), BK=16,
// 4 waves each owning a 64x32 wave tile = 8 double4 accumulators.
// Fragment maps (verified 16x16 pattern): A lane=(m=l&15, k=l>>4);
// B lane=(n=l&15, k=l>>4); D col=l&15, row=4*(l>>4)+reg.
// k order: 4-quads inside MFMA, quads ascending, k0 ascending, chunk s.
// Grid: (N/64, M/128, S). M%128==0, N%64==0, Kc%16==0.
// ---------------------------------------------------------------------------
__global__ __launch_bounds__(256) void gemm_nt_mfma_f64(
    const float* __restrict__ A, const float* __restrict__ B,
    double* __restrict__ P, int M, int N, int K, int Kc) {
  __shared__ double As[16][130];  // 16.6 KB
  __shared__ double Bs[16][66];   //  8.4 KB

  const int t = threadIdx.x;
  const int n0 = blockIdx.x * 64;
  const int m0 = blockIdx.y * 128;
  const int s  = blockIdx.z;
  const int kb = s * Kc;
  const int rS = t >> 2;            // 0..63 staging row
  const int cS = (t & 3) * 4;       // staging k offset 0,4,8,12
  const int w  = t >> 6;            // wave 0..3
  const int lane = t & 63;
  const int lq = lane >> 4;         // quad 0..3
  const int ln = lane & 15;
  const int mW = (w >> 1) * 64;     // wave m offset within block tile
  const int nW = (w & 1) * 32;      // wave n offset

  f64x4 acc[4][2];
#pragma unroll
  for (int g = 0; g < 4; ++g)
#pragma unroll
    for (int h = 0; h < 2; ++h) acc[g][h] = {0.0, 0.0, 0.0, 0.0};

  const float* Alo = &A[(size_t)(m0 + rS) * K + cS];
  const float* Ahi = &A[(size_t)(m0 + 64 + rS) * K + cS];
  const float* Bro = &B[(size_t)(n0 + rS) * K + cS];

  float4 a0 = *(const float4*)&Alo[kb];
  float4 a1 = *(const float4*)&Ahi[kb];
  float4 b0 = *(const float4*)&Bro[kb];

  for (int k0 = kb; k0 < kb + Kc; k0 += 16) {
    __syncthreads();
    As[cS + 0][rS] = (double)a0.x; As[cS + 1][rS] = (double)a0.y;
    As[cS + 2][rS] = (double)a0.z; As[cS + 3][rS] = (double)a0.w;
    As[cS + 0][64 + rS] = (double)a1.x; As[cS + 1][64 + rS] = (double)a1.y;
    As[cS + 2][64 + rS] = (double)a1.z; As[cS + 3][64 + rS] = (double)a1.w;
    Bs[cS + 0][rS] = (double)b0.x; Bs[cS + 1][rS] = (double)b0.y;
    Bs[cS + 2][rS] = (double)b0.z; Bs[cS + 3][rS] = (double)b0.w;
    if (k0 + 16 < kb + Kc) {  // prefetch next k-step during compute
      a0 = *(const float4*)&Alo[k0 + 16];
      a1 = *(const float4*)&Ahi[k0 + 16];
      b0 = *(const float4*)&Bro[k0 + 16];
    }
    __syncthreads();
#pragma unroll
    for (int kq = 0; kq < 4; ++kq) {
      const int kr = 4 * kq + lq;   // this lane's k row within the BK tile
      double aF[4], bF[2];
#pragma unroll
      for (int g = 0; g < 4; ++g) aF[g] = As[kr][mW + 16 * g + ln];
#pragma unroll
      for (int h = 0; h < 2; ++h) bF[h] = Bs[kr][nW + 16 * h + ln];
#pragma unroll
      for (int g = 0; g < 4; ++g)
#pragma unroll
        for (int h = 0; h < 2; ++h)
          acc[g][h] = __builtin_amdgcn_mfma_f64_16x16x4f64(aF[g], bF[h],
                                                           acc[g][h], 0, 0, 0);
    }
  }

  double* Pp = P + (size_t)s * M * N;
#pragma unroll
  for (int g = 0; g < 4; ++g) {
#pragma unroll
    for (int h = 0; h < 2; ++h) {
#pragma unroll
      for (int v = 0; v < 4; ++v) {
        const int row = m0 + mW + 16 * g + 4 * lq + v;
        const int col = n0 + nW + 16 * h + ln;
        Pp[(size_t)row * N + col] = acc[g][h][v];
      }
    }
  }
}

// ---------------------------------------------------------------------------
// Reduce S f64 partials (ascending) + tanh epilogue on the f32 grid.
// ---------------------------------------------------------------------------
__global__ __launch_bounds__(256) void reduce_tanh(
    const double* __restrict__ P, int S, const float* __restrict__ bias,
    float* __restrict__ C, int N, int total) {
  const int idx = blockIdx.x * 256 + threadIdx.x;
  if (idx >= total) return;
  double sum = 0.0;
  for (int s = 0; s < S; ++s) sum += P[(size_t)s * total + idx];
  const float zg = (float)sum;
  const float z = zg + bias[idx % N];
  C[idx] = (float)tanh((double)z);
}

// ---------------------------------------------------------------------------
// GEMM2 reduce + tanh + row-L2-normalize, fused (R6-proven).
// ---------------------------------------------------------------------------
__global__ __launch_bounds__(256) void reduce_tanh_norm(
    const double* __restrict__ P, int S, const float* __restrict__ bias,
    float* __restrict__ last, float* __restrict__ nrm) {
  const int b = blockIdx.x;
  const int t = threadIdx.x;
  const int idx = b * 256 + t;
  const int total = 1024 * 256;
  double sum = 0.0;
  for (int s = 0; s < S; ++s) sum += P[(size_t)s * total + idx];
  const float zg = (float)sum;
  const float z = zg + bias[t];
  const float v = (float)tanh((double)z);
  last[idx] = v;

  const float sq = v * v;
  double s = (double)sq;
#pragma unroll
  for (int o = 32; o > 0; o >>= 1) s += __shfl_down(s, o);
  __shared__ double red[4];
  if ((t & 63) == 0) red[t >> 6] = s;
  __syncthreads();
  const double totalSq = red[0] + red[1] + red[2] + red[3];
  const float s32 = (float)totalSq;
  const float den = sqrtf(s32) + 1e-12f;
  nrm[idx] = v / den;
}

// ---------------------------------------------------------------------------
// Gram + threshold adjacency, direct (R6-proven): 64x64 tile, f64 VALU acc.
// ---------------------------------------------------------------------------
__global__ __launch_bounds__(256) void gram_adj_direct(
    const float* __restrict__ Nrm, float* __restrict__ adj, int Msz, int K) {
  __shared__ double As[16][66];
  __shared__ double Bs[16][66];

  const int t = threadIdx.x;
  const int n0 = blockIdx.x * 64;
  const int m0 = blockIdx.y * 64;
  const int lm = t >> 2;
  const int lk4 = (t & 3) * 4;
  const int ty = t >> 4;
  const int tx = t & 15;

  double acc[4][4];
#pragma unroll
  for (int i = 0; i < 4; ++i)
#pragma unroll
    for (int j = 0; j < 4; ++j) acc[i][j] = 0.0;

  for (int k0 = 0; k0 < K; k0 += 16) {
    const float4 av = *(const float4*)&Nrm[(size_t)(m0 + lm) * K + k0 + lk4];
    const float4 bv = *(const float4*)&Nrm[(size_t)(n0 + lm) * K + k0 + lk4];
    __syncthreads();
    As[lk4 + 0][lm] = (double)av.x; As[lk4 + 1][lm] = (double)av.y;
    As[lk4 + 2][lm] = (double)av.z; As[lk4 + 3][lm] = (double)av.w;
    Bs[lk4 + 0][lm] = (double)bv.x; Bs[lk4 + 1][lm] = (double)bv.y;
    Bs[lk4 + 2][lm] = (double)bv.z; Bs[lk4 + 3][lm] = (double)bv.w;
    __syncthreads();
#pragma unroll
    for (int k = 0; k < 16; ++k) {
      const double2 a01 = *(const double2*)&As[k][2 * ty];
      const double2 a23 = *(const double2*)&As[k][32 + 2 * ty];
      const double2 b01 = *(const double2*)&Bs[k][2 * tx];
      const double2 b23 = *(const double2*)&Bs[k][32 + 2 * tx];
      const double ar[4] = {a01.x, a01.y, a23.x, a23.y};
      const double br[4] = {b01.x, b01.y, b23.x, b23.y};
#pragma unroll
      for (int i = 0; i < 4; ++i)
#pragma unroll
        for (int j = 0; j < 4; ++j)
          acc[i][j] = fma(ar[i], br[j], acc[i][j]);
    }
  }

  const int rows[4] = {m0 + 2 * ty, m0 + 2 * ty + 1,
                       m0 + 32 + 2 * ty, m0 + 32 + 2 * ty + 1};
  const int cols[4] = {n0 + 2 * tx, n0 + 2 * tx + 1,
                       n0 + 32 + 2 * tx, n0 + 32 + 2 * tx + 1};
#pragma unroll
  for (int i = 0; i < 4; ++i)
#pragma unroll
    for (int j = 0; j < 4; ++j) {
      const float g = (float)acc[i][j];
      const float fid = g * g;
      float v = (fid >= 0.8f) ? 1.0f : ((fid >= 0.6f) ? 0.5f : 0.0f);
      if (rows[i] == cols[j]) v = 0.0f;
      adj[(size_t)rows[i] * Msz + cols[j]] = v;
    }
}

// ---------------------------------------------------------------------------
// BatchNorm1d training mode (unchanged, proven).
// ---------------------------------------------------------------------------
__global__ __launch_bounds__(256) void bn_stats(
    const float* __restrict__ last, const float* __restrict__ gamma,
    const float* __restrict__ beta, float* __restrict__ out) {
  const int j = blockIdx.x;
  const int t = threadIdx.x;
  double v[4];
  double s = 0.0;
#pragma unroll
  for (int i = 0; i < 4; ++i) {
    v[i] = (double)last[(size_t)(i * 256 + t) * 256 + j];
    s += v[i];
  }
#pragma unroll
  for (int o = 32; o > 0; o >>= 1) s += __shfl_down(s, o);
  __shared__ double red[4];
  if ((t & 63) == 0) red[t >> 6] = s;
  __syncthreads();
  const double mean = (red[0] + red[1] + red[2] + red[3]) * (1.0 / 1024.0);
  double q = 0.0;
#pragma unroll
  for (int i = 0; i < 4; ++i) {
    const double d = v[i] - mean;
    q += d * d;
  }
#pragma unroll
  for (int o = 32; o > 0; o >>= 1) q += __shfl_down(q, o);
  __syncthreads();
  if ((t & 63) == 0) red[t >> 6] = q;
  __syncthreads();
  const double var = (red[0] + red[1] + red[2] + red[3]) * (1.0 / 1024.0);
  const double g = (double)gamma[j] / sqrt(var + 1e-5);
  const double be = (double)beta[j];
#pragma unroll
  for (int i = 0; i < 4; ++i)
    out[(size_t)(i * 256 + t) * 256 + j] = (float)((v[i] - mean) * g + be);
}

// ---------------------------------------------------------------------------
extern "C" void kernel_launch(void* const* d_in, const int* in_sizes, int n_in,
                              void* d_out, int out_size, void* d_ws,
                              size_t ws_size, hipStream_t stream) {
  const float* x     = (const float*)d_in[0];
  const float* cw1   = (const float*)d_in[1];
  const float* cb1   = (const float*)d_in[2];
  const float* cw2   = (const float*)d_in[3];
  const float* cb2   = (const float*)d_in[4];
  const float* w1    = (const float*)d_in[5];   // [1024,4096]
  const float* b1    = (const float*)d_in[6];
  const float* w2    = (const float*)d_in[7];   // [256,1024]
  const float* b2    = (const float*)d_in[8];
  const float* gamma = (const float*)d_in[9];
  const float* beta  = (const float*)d_in[10];

  float* outp = (float*)d_out;            // [1024,256]
  float* adj  = outp + 1024 * 256;        // [1024,1024]

  float* ws   = (float*)d_ws;
  float* flat = ws;                       // [1024,4096] @0        16.78 MB
  float* h1   = ws + 4194304;             // [1024,1024]            4.19 MB
  float* last = ws + 5242880;             // [1024,256]             1.05 MB
  float* nrm  = ws + 5505024;             // [1024,256]             1.05 MB
  double* part = (double*)(ws + 5767168); // partial region @23.07 MB
  float* feat1 = (float*)part;            // [1024,8,32,32] 33.55 MB,
                                          // dead before first GEMM

  // ws gates (deterministic): S1=8 -> 90.2 MB total; 4 -> 56.6 MB;
  // else 2 + fused conv (feat1 wouldn't fit).
  const size_t baseB = 5767168ull * 4ull;
  int S1;
  if (ws_size >= baseB + 8ull * 1024 * 1024 * 8) S1 = 8;
  else if (ws_size >= baseB + 4ull * 1024 * 1024 * 8) S1 = 4;
  else S1 = 2;
  const int S2 = (S1 >= 4) ? 16 : 4;      // gemm2 partials: 33.5MB / 8.4MB
  const bool split_conv = (S1 >= 4);

  if (split_conv) {
    conv1_kernel<<<1024, 256, 0, stream>>>(x, cw1, cb1, feat1);
    conv2_kernel<<<1024, 256, 0, stream>>>(feat1, cw2, cb2, flat);
  } else {
    conv_fused<<<1024, 256, 0, stream>>>(x, cw1, cb1, cw2, cb2, flat);
  }

  // h1 = tanh(flat @ w1^T + b1)   [1024,1024], K=4096  (MFMA f64)
  gemm_nt_mfma_f64<<<dim3(16, 8, S1), 256, 0, stream>>>(
      flat, w1, part, 1024, 1024, 4096, 4096 / S1);
  reduce_tanh<<<4096, 256, 0, stream>>>(part, S1, b1, h1, 1024, 1024 * 1024);

  // last = tanh(h1 @ w2^T + b2), then rownorm, fused reduce  (MFMA f64)
  gemm_nt_mfma_f64<<<dim3(4, 8, S2), 256, 0, stream>>>(
      h1, w2, part, 1024, 256, 1024, 1024 / S2);
  reduce_tanh_norm<<<1024, 256, 0, stream>>>(part, S2, b2, last, nrm);

  // adj = thr((nrm @ nrm^T)^2), zero diag; K=256, direct (no partials)
  gram_adj_direct<<<dim3(16, 16), 256, 0, stream>>>(nrm, adj, 1024, 256);

  bn_stats<<<256, 256, 0, stream>>>(last, gamma, beta, outp);
}

// Round 10
// 395.141 us; speedup vs baseline: 1.0799x; 1.0799x over previous
//
#include <hip/hip_runtime.h>
#include <hip/hip_bf16.h>
#include <math.h>

// ===========================================================================
// f64-accumulate / f32-storage-grid pipeline (R2/R3 numerics, proven).
// R9: R8's 1.0-magnitude adjacency failure was structural, not numeric.
// Reverts the two R8 suspects: (a) gram back to the R7-proven VALU kernel;
// (b) GEMM back to the two-barrier single-buffer sync (proven R3-R7) while
// keeping the 128x128 tile whose store mapping R8's output-0 pass verified.
// k order: quads inside MFMA, quads ascending, k0 ascending (== R7 pass).
// ===========================================================================

typedef double f64x4 __attribute__((ext_vector_type(4)));

// ---------------------------------------------------------------------------
// conv1: conv(1->8,3x3,SAME) + bias + relu + maxpool2 -> feat1 [1024,8,32,32]
// ---------------------------------------------------------------------------
__global__ __launch_bounds__(256) void conv1_kernel(
    const float* __restrict__ x, const float* __restrict__ cw1,
    const float* __restrict__ cb1, float* __restrict__ feat1) {
  __shared__ float sX[66 * 66];
  __shared__ float sW1[72];
  __shared__ float sB1[8];

  const int b = blockIdx.x;
  const int t = threadIdx.x;

  for (int i = t; i < 66 * 66; i += 256) sX[i] = 0.0f;
  if (t < 72) sW1[t] = cw1[t];
  if (t < 8)  sB1[t] = cb1[t];
  __syncthreads();

  const float* xb = x + (size_t)b * 4096;
  for (int i = t; i < 4096; i += 256)
    sX[((i >> 6) + 1) * 66 + (i & 63) + 1] = xb[i];
  __syncthreads();

  for (int task = t; task < 2048; task += 256) {
    const int ch = task >> 8;
    const int rem = task & 255;
    const int py = rem >> 3;
    const int px0 = (rem & 7) * 4;

    double w9[9];
#pragma unroll
    for (int k = 0; k < 9; ++k) w9[k] = (double)sW1[ch * 9 + k];

    float reg[4][10];
#pragma unroll
    for (int r = 0; r < 4; ++r)
#pragma unroll
      for (int c = 0; c < 5; ++c) {
        const float2 v =
            *(const float2*)&sX[(2 * py + r) * 66 + 2 * px0 + 2 * c];
        reg[r][2 * c] = v.x;
        reg[r][2 * c + 1] = v.y;
      }

    float out4[4];
#pragma unroll
    for (int px = 0; px < 4; ++px) {
      double best = -1e300;
#pragma unroll
      for (int dy = 0; dy < 2; ++dy) {
#pragma unroll
        for (int dx = 0; dx < 2; ++dx) {
          double s = 0.0;
#pragma unroll
          for (int ky = 0; ky < 3; ++ky)
#pragma unroll
            for (int kx = 0; kx < 3; ++kx)
              s = fma((double)reg[dy + ky][2 * px + dx + kx], w9[ky * 3 + kx],
                      s);
          best = fmax(best, s);
        }
      }
      out4[px] = (float)fmax(best + (double)sB1[ch], 0.0);
    }
    *(float4*)&feat1[(size_t)b * 8192 + ch * 1024 + py * 32 + px0] =
        make_float4(out4[0], out4[1], out4[2], out4[3]);
  }
}

// ---------------------------------------------------------------------------
// conv2 (R5-proven, no spill): conv(8->16)+bias+relu+pool -> flat [1024,4096]
// ---------------------------------------------------------------------------
__global__ __launch_bounds__(256) void conv2_kernel(
    const float* __restrict__ feat1, const float* __restrict__ cw2,
    const float* __restrict__ cb2, float* __restrict__ flat) {
  __shared__ float sF[8 * 34 * 34];
  __shared__ float sW2[1152];
  __shared__ float sB2[16];

  const int b = blockIdx.x;
  const int t = threadIdx.x;

  for (int i = t; i < 8 * 34 * 34; i += 256) sF[i] = 0.0f;
  for (int i = t; i < 1152; i += 256) sW2[i] = cw2[i];
  if (t < 16) sB2[t] = cb2[t];
  __syncthreads();

  const float* fb = feat1 + (size_t)b * 8192;
  for (int i = t; i < 8192; i += 256) {
    const int ch = i >> 10, pos = i & 1023;
    sF[ch * 1156 + ((pos >> 5) + 1) * 34 + (pos & 31) + 1] = fb[i];
  }
  __syncthreads();

  const int py = t >> 4, px = t & 15;
  float* ob = flat + (size_t)b * 4096 + py * 16 + px;

#pragma unroll 1
  for (int oh = 0; oh < 2; ++oh) {
    double acc[8][4];
#pragma unroll
    for (int o = 0; o < 8; ++o)
#pragma unroll
      for (int q = 0; q < 4; ++q) acc[o][q] = 0.0;

#pragma unroll
    for (int ic = 0; ic < 8; ++ic) {
      float r[4][4];
#pragma unroll
      for (int iy = 0; iy < 4; ++iy) {
        const float2 v0 =
            *(const float2*)&sF[ic * 1156 + (2 * py + iy) * 34 + 2 * px];
        const float2 v1 =
            *(const float2*)&sF[ic * 1156 + (2 * py + iy) * 34 + 2 * px + 2];
        r[iy][0] = v0.x; r[iy][1] = v0.y; r[iy][2] = v1.x; r[iy][3] = v1.y;
      }
#pragma unroll
      for (int o = 0; o < 8; ++o) {
        const float* w = &sW2[(oh * 8 + o) * 72 + ic * 9];
        double w9[9];
#pragma unroll
        for (int k = 0; k < 9; ++k) w9[k] = (double)w[k];
#pragma unroll
        for (int dy = 0; dy < 2; ++dy)
#pragma unroll
          for (int dx = 0; dx < 2; ++dx) {
            double s = acc[o][dy * 2 + dx];
#pragma unroll
            for (int ky = 0; ky < 3; ++ky)
#pragma unroll
              for (int kx = 0; kx < 3; ++kx)
                s = fma((double)r[dy + ky][dx + kx], w9[ky * 3 + kx], s);
            acc[o][dy * 2 + dx] = s;
          }
      }
    }
#pragma unroll
    for (int o = 0; o < 8; ++o) {
      const int oc = oh * 8 + o;
      const double best =
          fmax(fmax(acc[o][0], acc[o][1]), fmax(acc[o][2], acc[o][3]));
      ob[oc * 256] = (float)fmax(best + (double)sB2[oc], 0.0);
    }
  }
}

// ---------------------------------------------------------------------------
// Fallback fused conv (R2/R3 kernel) for small-ws path.
// ---------------------------------------------------------------------------
__global__ __launch_bounds__(256) void conv_fused(
    const float* __restrict__ x,
    const float* __restrict__ cw1, const float* __restrict__ cb1,
    const float* __restrict__ cw2, const float* __restrict__ cb2,
    float* __restrict__ flat) {
  __shared__ float sX[66 * 66];
  __shared__ float sF[8 * 34 * 34];
  __shared__ float sW1[72];
  __shared__ float sW2[1152];
  __shared__ float sB1[8];
  __shared__ float sB2[16];

  const int b = blockIdx.x;
  const int t = threadIdx.x;

  for (int i = t; i < 66 * 66; i += 256) sX[i] = 0.0f;
  for (int i = t; i < 8 * 34 * 34; i += 256) sF[i] = 0.0f;
  if (t < 72) sW1[t] = cw1[t];
  for (int i = t; i < 1152; i += 256) sW2[i] = cw2[i];
  if (t < 8)  sB1[t] = cb1[t];
  if (t < 16) sB2[t] = cb2[t];
  __syncthreads();

  const float* xb = x + (size_t)b * 4096;
  for (int i = t; i < 4096; i += 256)
    sX[((i >> 6) + 1) * 66 + (i & 63) + 1] = xb[i];
  __syncthreads();

  for (int p = t; p < 8192; p += 256) {
    const int ch = p >> 10, pos = p & 1023;
    const int py1 = pos >> 5, px1 = pos & 31;
    double best = -1e300;
#pragma unroll
    for (int dy = 0; dy < 2; ++dy)
#pragma unroll
      for (int dx = 0; dx < 2; ++dx) {
        const int y = 2 * py1 + dy, xx = 2 * px1 + dx;
        double s = 0.0;
#pragma unroll
        for (int ky = 0; ky < 3; ++ky)
#pragma unroll
          for (int kx = 0; kx < 3; ++kx)
            s = fma((double)sX[(y + ky) * 66 + xx + kx],
                    (double)sW1[ch * 9 + ky * 3 + kx], s);
        best = fmax(best, s);
      }
    sF[ch * 1156 + (py1 + 1) * 34 + px1 + 1] =
        (float)fmax(best + (double)sB1[ch], 0.0);
  }
  __syncthreads();

  const int py = t >> 4, px = t & 15;
  for (int oh = 0; oh < 2; ++oh) {
    double acc[8][4];
#pragma unroll
    for (int o = 0; o < 8; ++o)
#pragma unroll
      for (int q = 0; q < 4; ++q) acc[o][q] = 0.0;
#pragma unroll
    for (int ic = 0; ic < 8; ++ic) {
      double r[4][4];
#pragma unroll
      for (int iy = 0; iy < 4; ++iy)
#pragma unroll
        for (int ix = 0; ix < 4; ++ix)
          r[iy][ix] = (double)sF[ic * 1156 + (2 * py + iy) * 34 + 2 * px + ix];
#pragma unroll
      for (int o = 0; o < 8; ++o) {
        const float* w = &sW2[(oh * 8 + o) * 72 + ic * 9];
        double w9[9];
#pragma unroll
        for (int k = 0; k < 9; ++k) w9[k] = (double)w[k];
#pragma unroll
        for (int dy = 0; dy < 2; ++dy)
#pragma unroll
          for (int dx = 0; dx < 2; ++dx) {
            double s = acc[o][dy * 2 + dx];
#pragma unroll
            for (int ky = 0; ky < 3; ++ky)
#pragma unroll
              for (int kx = 0; kx < 3; ++kx)
                s = fma(r[dy + ky][dx + kx], w9[ky * 3 + kx], s);
            acc[o][dy * 2 + dx] = s;
          }
      }
    }
    float* ob = flat + (size_t)b * 4096 + py * 16 + px;
#pragma unroll
    for (int o = 0; o < 8; ++o) {
      const int oc = oh * 8 + o;
      double best =
          fmax(fmax(acc[o][0], acc[o][1]), fmax(acc[o][2], acc[o][3]));
      ob[oc * 256] = (float)fmax(best + (double)sB2[oc], 0.0);
    }
  }
}

// ---------------------------------------------------------------------------
// Split-K NT GEMM via v_mfma_f64_16x16x4: block tile 128(M)x128(N), BK=16,
// 4 waves each owning a 64x64 wave tile = 16 f64x4 accumulators.
// TWO-BARRIER single-buffer sync (proven R3-R7; R8's one-barrier dbuf
// reverted). Store mapping verified by R8's output-0 pass.
// k order: 4-quads inside MFMA, quads ascending, k0 ascending (== R7).
// Grid: (N/128, M/128, S). M%128==0, N%128==0, Kc%16==0.
// ---------------------------------------------------------------------------
__global__ __launch_bounds__(256, 2) void gemm_mfma_128(
    const float* __restrict__ A, const float* __restrict__ B,
    double* __restrict__ P, int M, int N, int K, int Kc) {
  __shared__ double As[16][131];  // 16.8 KB
  __shared__ double Bs[16][131];  // 16.8 KB

  const int t = threadIdx.x;
  const int n0 = blockIdx.x * 128;
  const int m0 = blockIdx.y * 128;
  const int s  = blockIdx.z;
  const int kb = s * Kc;
  const int rS = t >> 2;            // 0..63 staging row
  const int cS = (t & 3) * 4;       // staging k offset 0,4,8,12
  const int w  = t >> 6;            // wave 0..3
  const int lane = t & 63;
  const int lq = lane >> 4;         // quad 0..3
  const int ln = lane & 15;
  const int mW = (w >> 1) * 64;     // wave m offset
  const int nW = (w & 1) * 64;      // wave n offset

  f64x4 acc[4][4];
#pragma unroll
  for (int g = 0; g < 4; ++g)
#pragma unroll
    for (int h = 0; h < 4; ++h) acc[g][h] = {0.0, 0.0, 0.0, 0.0};

  const float* Alo = &A[(size_t)(m0 + rS) * K + cS];
  const float* Ahi = &A[(size_t)(m0 + 64 + rS) * K + cS];
  const float* Blo = &B[(size_t)(n0 + rS) * K + cS];
  const float* Bhi = &B[(size_t)(n0 + 64 + rS) * K + cS];

  float4 a0 = *(const float4*)&Alo[kb];
  float4 a1 = *(const float4*)&Ahi[kb];
  float4 b0 = *(const float4*)&Blo[kb];
  float4 b1 = *(const float4*)&Bhi[kb];

  for (int k0 = kb; k0 < kb + Kc; k0 += 16) {
    __syncthreads();  // previous iteration's compute (reads) done
    As[cS + 0][rS] = (double)a0.x; As[cS + 1][rS] = (double)a0.y;
    As[cS + 2][rS] = (double)a0.z; As[cS + 3][rS] = (double)a0.w;
    As[cS + 0][64 + rS] = (double)a1.x; As[cS + 1][64 + rS] = (double)a1.y;
    As[cS + 2][64 + rS] = (double)a1.z; As[cS + 3][64 + rS] = (double)a1.w;
    Bs[cS + 0][rS] = (double)b0.x; Bs[cS + 1][rS] = (double)b0.y;
    Bs[cS + 2][rS] = (double)b0.z; Bs[cS + 3][rS] = (double)b0.w;
    Bs[cS + 0][64 + rS] = (double)b1.x; Bs[cS + 1][64 + rS] = (double)b1.y;
    Bs[cS + 2][64 + rS] = (double)b1.z; Bs[cS + 3][64 + rS] = (double)b1.w;
    if (k0 + 16 < kb + Kc) {  // prefetch next K-step (overlaps compute)
      a0 = *(const float4*)&Alo[k0 + 16];
      a1 = *(const float4*)&Ahi[k0 + 16];
      b0 = *(const float4*)&Blo[k0 + 16];
      b1 = *(const float4*)&Bhi[k0 + 16];
    }
    __syncthreads();  // writes visible
#pragma unroll
    for (int kq = 0; kq < 4; ++kq) {
      const int kr = 4 * kq + lq;
      double aF[4], bF[4];
#pragma unroll
      for (int g = 0; g < 4; ++g) aF[g] = As[kr][mW + 16 * g + ln];
#pragma unroll
      for (int h = 0; h < 4; ++h) bF[h] = Bs[kr][nW + 16 * h + ln];
#pragma unroll
      for (int g = 0; g < 4; ++g)
#pragma unroll
        for (int h = 0; h < 4; ++h)
          acc[g][h] = __builtin_amdgcn_mfma_f64_16x16x4f64(aF[g], bF[h],
                                                           acc[g][h], 0, 0, 0);
    }
  }

  double* Pp = P + (size_t)s * M * N;
#pragma unroll
  for (int g = 0; g < 4; ++g) {
#pragma unroll
    for (int h = 0; h < 4; ++h) {
#pragma unroll
      for (int v = 0; v < 4; ++v) {
        const int row = m0 + mW + 16 * g + 4 * lq + v;
        const int col = n0 + nW + 16 * h + ln;
        Pp[(size_t)row * N + col] = acc[g][h][v];
      }
    }
  }
}

// ---------------------------------------------------------------------------
// Reduce S f64 partials (ascending) + tanh epilogue on the f32 grid.
// ---------------------------------------------------------------------------
__global__ __launch_bounds__(256) void reduce_tanh(
    const double* __restrict__ P, int S, const float* __restrict__ bias,
    float* __restrict__ C, int N, int total) {
  const int idx = blockIdx.x * 256 + threadIdx.x;
  if (idx >= total) return;
  double sum = 0.0;
  for (int s = 0; s < S; ++s) sum += P[(size_t)s * total + idx];
  const float zg = (float)sum;
  const float z = zg + bias[idx & (N - 1)];
  C[idx] = (float)tanh((double)z);
}

// ---------------------------------------------------------------------------
// GEMM2 reduce + tanh + row-L2-normalize, fused (R6/R7-proven).
// ---------------------------------------------------------------------------
__global__ __launch_bounds__(256) void reduce_tanh_norm(
    const double* __restrict__ P, int S, const float* __restrict__ bias,
    float* __restrict__ last, float* __restrict__ nrm) {
  const int b = blockIdx.x;
  const int t = threadIdx.x;
  const int idx = b * 256 + t;
  const int total = 1024 * 256;
  double sum = 0.0;
  for (int s = 0; s < S; ++s) sum += P[(size_t)s * total + idx];
  const float zg = (float)sum;
  const float z = zg + bias[t];
  const float v = (float)tanh((double)z);
  last[idx] = v;

  const float sq = v * v;
  double s = (double)sq;
#pragma unroll
  for (int o = 32; o > 0; o >>= 1) s += __shfl_down(s, o);
  __shared__ double red[4];
  if ((t & 63) == 0) red[t >> 6] = s;
  __syncthreads();
  const double totalSq = red[0] + red[1] + red[2] + red[3];
  const float s32 = (float)totalSq;
  const float den = sqrtf(s32) + 1e-12f;
  nrm[idx] = v / den;
}

// ---------------------------------------------------------------------------
// Gram + threshold adjacency, direct (R6/R7-PROVEN VALU kernel, restored):
// 64x64 tile, BK=16, 4x4 microtile, f64 accumulate k ascending, K=256.
// g = f32(acc); fid = g*g; 0.8f/0.6f cutoffs; diag zeroed.
// ---------------------------------------------------------------------------
__global__ __launch_bounds__(256) void gram_adj_direct(
    const float* __restrict__ Nrm, float* __restrict__ adj, int Msz, int K) {
  __shared__ double As[16][66];
  __shared__ double Bs[16][66];

  const int t = threadIdx.x;
  const int n0 = blockIdx.x * 64;
  const int m0 = blockIdx.y * 64;
  const int lm = t >> 2;
  const int lk4 = (t & 3) * 4;
  const int ty = t >> 4;
  const int tx = t & 15;

  double acc[4][4];
#pragma unroll
  for (int i = 0; i < 4; ++i)
#pragma unroll
    for (int j = 0; j < 4; ++j) acc[i][j] = 0.0;

  for (int k0 = 0; k0 < K; k0 += 16) {
    const float4 av = *(const float4*)&Nrm[(size_t)(m0 + lm) * K + k0 + lk4];
    const float4 bv = *(const float4*)&Nrm[(size_t)(n0 + lm) * K + k0 + lk4];
    __syncthreads();
    As[lk4 + 0][lm] = (double)av.x; As[lk4 + 1][lm] = (double)av.y;
    As[lk4 + 2][lm] = (double)av.z; As[lk4 + 3][lm] = (double)av.w;
    Bs[lk4 + 0][lm] = (double)bv.x; Bs[lk4 + 1][lm] = (double)bv.y;
    Bs[lk4 + 2][lm] = (double)bv.z; Bs[lk4 + 3][lm] = (double)bv.w;
    __syncthreads();
#pragma unroll
    for (int k = 0; k < 16; ++k) {
      const double2 a01 = *(const double2*)&As[k][2 * ty];
      const double2 a23 = *(const double2*)&As[k][32 + 2 * ty];
      const double2 b01 = *(const double2*)&Bs[k][2 * tx];
      const double2 b23 = *(const double2*)&Bs[k][32 + 2 * tx];
      const double ar[4] = {a01.x, a01.y, a23.x, a23.y};
      const double br[4] = {b01.x, b01.y, b23.x, b23.y};
#pragma unroll
      for (int i = 0; i < 4; ++i)
#pragma unroll
        for (int j = 0; j < 4; ++j)
          acc[i][j] = fma(ar[i], br[j], acc[i][j]);
    }
  }

  const int rows[4] = {m0 + 2 * ty, m0 + 2 * ty + 1,
                       m0 + 32 + 2 * ty, m0 + 32 + 2 * ty + 1};
  const int cols[4] = {n0 + 2 * tx, n0 + 2 * tx + 1,
                       n0 + 32 + 2 * tx, n0 + 32 + 2 * tx + 1};
#pragma unroll
  for (int i = 0; i < 4; ++i)
#pragma unroll
    for (int j = 0; j < 4; ++j) {
      const float g = (float)acc[i][j];
      const float fid = g * g;
      float v = (fid >= 0.8f) ? 1.0f : ((fid >= 0.6f) ? 0.5f : 0.0f);
      if (rows[i] == cols[j]) v = 0.0f;
      adj[(size_t)rows[i] * Msz + cols[j]] = v;
    }
}

// ---------------------------------------------------------------------------
// BatchNorm1d training mode (unchanged, proven).
// ---------------------------------------------------------------------------
__global__ __launch_bounds__(256) void bn_stats(
    const float* __restrict__ last, const float* __restrict__ gamma,
    const float* __restrict__ beta, float* __restrict__ out) {
  const int j = blockIdx.x;
  const int t = threadIdx.x;
  double v[4];
  double s = 0.0;
#pragma unroll
  for (int i = 0; i < 4; ++i) {
    v[i] = (double)last[(size_t)(i * 256 + t) * 256 + j];
    s += v[i];
  }
#pragma unroll
  for (int o = 32; o > 0; o >>= 1) s += __shfl_down(s, o);
  __shared__ double red[4];
  if ((t & 63) == 0) red[t >> 6] = s;
  __syncthreads();
  const double mean = (red[0] + red[1] + red[2] + red[3]) * (1.0 / 1024.0);
  double q = 0.0;
#pragma unroll
  for (int i = 0; i < 4; ++i) {
    const double d = v[i] - mean;
    q += d * d;
  }
#pragma unroll
  for (int o = 32; o > 0; o >>= 1) q += __shfl_down(q, o);
  __syncthreads();
  if ((t & 63) == 0) red[t >> 6] = q;
  __syncthreads();
  const double var = (red[0] + red[1] + red[2] + red[3]) * (1.0 / 1024.0);
  const double g = (double)gamma[j] / sqrt(var + 1e-5);
  const double be = (double)beta[j];
#pragma unroll
  for (int i = 0; i < 4; ++i)
    out[(size_t)(i * 256 + t) * 256 + j] = (float)((v[i] - mean) * g + be);
}

// ---------------------------------------------------------------------------
extern "C" void kernel_launch(void* const* d_in, const int* in_sizes, int n_in,
                              void* d_out, int out_size, void* d_ws,
                              size_t ws_size, hipStream_t stream) {
  const float* x     = (const float*)d_in[0];
  const float* cw1   = (const float*)d_in[1];
  const float* cb1   = (const float*)d_in[2];
  const float* cw2   = (const float*)d_in[3];
  const float* cb2   = (const float*)d_in[4];
  const float* w1    = (const float*)d_in[5];   // [1024,4096]
  const float* b1    = (const float*)d_in[6];
  const float* w2    = (const float*)d_in[7];   // [256,1024]
  const float* b2    = (const float*)d_in[8];
  const float* gamma = (const float*)d_in[9];
  const float* beta  = (const float*)d_in[10];

  float* outp = (float*)d_out;            // [1024,256]
  float* adj  = outp + 1024 * 256;        // [1024,1024]

  float* ws   = (float*)d_ws;
  float* flat = ws;                       // [1024,4096] @0        16.78 MB
  float* h1   = ws + 4194304;             // [1024,1024]            4.19 MB
  float* last = ws + 5242880;             // [1024,256]             1.05 MB
  float* nrm  = ws + 5505024;             // [1024,256]             1.05 MB
  double* part = (double*)(ws + 5767168); // partial region @23.07 MB
  float* feat1 = (float*)part;            // [1024,8,32,32] 33.55 MB,
                                          // dead before first GEMM

  // ws gates (deterministic): S1=8 -> 90.2 MB total; 4 -> 56.6 MB;
  // else 2 + fused conv (feat1 wouldn't fit).
  const size_t baseB = 5767168ull * 4ull;
  int S1;
  if (ws_size >= baseB + 8ull * 1024 * 1024 * 8) S1 = 8;
  else if (ws_size >= baseB + 4ull * 1024 * 1024 * 8) S1 = 4;
  else S1 = 2;
  const int S2 = (S1 >= 4) ? 16 : 4;      // gemm2 partials: 33.5MB / 8.4MB
  const bool split_conv = (S1 >= 4);

  if (split_conv) {
    conv1_kernel<<<1024, 256, 0, stream>>>(x, cw1, cb1, feat1);
    conv2_kernel<<<1024, 256, 0, stream>>>(feat1, cw2, cb2, flat);
  } else {
    conv_fused<<<1024, 256, 0, stream>>>(x, cw1, cb1, cw2, cb2, flat);
  }

  // h1 = tanh(flat @ w1^T + b1)   [1024,1024], K=4096  (MFMA f64, 128x128)
  gemm_mfma_128<<<dim3(8, 8, S1), 256, 0, stream>>>(
      flat, w1, part, 1024, 1024, 4096, 4096 / S1);
  reduce_tanh<<<4096, 256, 0, stream>>>(part, S1, b1, h1, 1024, 1024 * 1024);

  // last = tanh(h1 @ w2^T + b2), then rownorm, fused reduce  (MFMA f64)
  gemm_mfma_128<<<dim3(2, 8, S2), 256, 0, stream>>>(
      h1, w2, part, 1024, 256, 1024, 1024 / S2);
  reduce_tanh_norm<<<1024, 256, 0, stream>>>(part, S2, b2, last, nrm);

  // adj = thr((nrm @ nrm^T)^2), zero diag; K=256, direct (PROVEN VALU)
  gram_adj_direct<<<dim3(16, 16), 256, 0, stream>>>(nrm, adj, 1024, 256);

  bn_stats<<<256, 256, 0, stream>>>(last, gamma, beta, outp);
}

// Round 11
// 393.999 us; speedup vs baseline: 1.0830x; 1.0029x over previous
//
#include <hip/hip_runtime.h>
#include <hip/hip_bf16.h>
#include <math.h>

// ===========================================================================
// R10: GEMM1 via int8 Ozaki slicing (exact i32 MFMA accumulation).
// Each f32 input row is scaled by an exact power of two, quantized to a
// 31-bit integer, and split into 4 int8 slices (shifts 24/17/10/3, offset-
// floor split -> slices in [-64,64], residual < 4). 13 slice-pair passes in
// 5 weight groups accumulate EXACTLY in i32 (no rounding, no order
// sensitivity); one f64 combine + f32-grid tanh epilogue per output.
// Method error ~2e-8 rel -- below the ~1e-7 deviation class the adjacency
// razor empirically tolerates. Eliminates split-K partials + reduce_tanh.
// Everything else: R9 (proven).
// ===========================================================================

typedef double f64x4 __attribute__((ext_vector_type(4)));
typedef int v4i __attribute__((ext_vector_type(4)));

#if defined(__has_builtin)
#if __has_builtin(__builtin_amdgcn_mfma_i32_16x16x64_i8)
#define HAVE_I8_MFMA 1
#endif
#endif
#ifndef HAVE_I8_MFMA
#define HAVE_I8_MFMA 0
#endif

// ---------------------------------------------------------------------------
// conv1 (R9-proven)
// ---------------------------------------------------------------------------
__global__ __launch_bounds__(256) void conv1_kernel(
    const float* __restrict__ x, const float* __restrict__ cw1,
    const float* __restrict__ cb1, float* __restrict__ feat1) {
  __shared__ float sX[66 * 66];
  __shared__ float sW1[72];
  __shared__ float sB1[8];

  const int b = blockIdx.x;
  const int t = threadIdx.x;

  for (int i = t; i < 66 * 66; i += 256) sX[i] = 0.0f;
  if (t < 72) sW1[t] = cw1[t];
  if (t < 8)  sB1[t] = cb1[t];
  __syncthreads();

  const float* xb = x + (size_t)b * 4096;
  for (int i = t; i < 4096; i += 256)
    sX[((i >> 6) + 1) * 66 + (i & 63) + 1] = xb[i];
  __syncthreads();

  for (int task = t; task < 2048; task += 256) {
    const int ch = task >> 8;
    const int rem = task & 255;
    const int py = rem >> 3;
    const int px0 = (rem & 7) * 4;

    double w9[9];
#pragma unroll
    for (int k = 0; k < 9; ++k) w9[k] = (double)sW1[ch * 9 + k];

    float reg[4][10];
#pragma unroll
    for (int r = 0; r < 4; ++r)
#pragma unroll
      for (int c = 0; c < 5; ++c) {
        const float2 v =
            *(const float2*)&sX[(2 * py + r) * 66 + 2 * px0 + 2 * c];
        reg[r][2 * c] = v.x;
        reg[r][2 * c + 1] = v.y;
      }

    float out4[4];
#pragma unroll
    for (int px = 0; px < 4; ++px) {
      double best = -1e300;
#pragma unroll
      for (int dy = 0; dy < 2; ++dy) {
#pragma unroll
        for (int dx = 0; dx < 2; ++dx) {
          double s = 0.0;
#pragma unroll
          for (int ky = 0; ky < 3; ++ky)
#pragma unroll
            for (int kx = 0; kx < 3; ++kx)
              s = fma((double)reg[dy + ky][2 * px + dx + kx], w9[ky * 3 + kx],
                      s);
          best = fmax(best, s);
        }
      }
      out4[px] = (float)fmax(best + (double)sB1[ch], 0.0);
    }
    *(float4*)&feat1[(size_t)b * 8192 + ch * 1024 + py * 32 + px0] =
        make_float4(out4[0], out4[1], out4[2], out4[3]);
  }
}

// ---------------------------------------------------------------------------
// conv2 (R5/R9-proven, no spill)
// ---------------------------------------------------------------------------
__global__ __launch_bounds__(256) void conv2_kernel(
    const float* __restrict__ feat1, const float* __restrict__ cw2,
    const float* __restrict__ cb2, float* __restrict__ flat) {
  __shared__ float sF[8 * 34 * 34];
  __shared__ float sW2[1152];
  __shared__ float sB2[16];

  const int b = blockIdx.x;
  const int t = threadIdx.x;

  for (int i = t; i < 8 * 34 * 34; i += 256) sF[i] = 0.0f;
  for (int i = t; i < 1152; i += 256) sW2[i] = cw2[i];
  if (t < 16) sB2[t] = cb2[t];
  __syncthreads();

  const float* fb = feat1 + (size_t)b * 8192;
  for (int i = t; i < 8192; i += 256) {
    const int ch = i >> 10, pos = i & 1023;
    sF[ch * 1156 + ((pos >> 5) + 1) * 34 + (pos & 31) + 1] = fb[i];
  }
  __syncthreads();

  const int py = t >> 4, px = t & 15;
  float* ob = flat + (size_t)b * 4096 + py * 16 + px;

#pragma unroll 1
  for (int oh = 0; oh < 2; ++oh) {
    double acc[8][4];
#pragma unroll
    for (int o = 0; o < 8; ++o)
#pragma unroll
      for (int q = 0; q < 4; ++q) acc[o][q] = 0.0;

#pragma unroll
    for (int ic = 0; ic < 8; ++ic) {
      float r[4][4];
#pragma unroll
      for (int iy = 0; iy < 4; ++iy) {
        const float2 v0 =
            *(const float2*)&sF[ic * 1156 + (2 * py + iy) * 34 + 2 * px];
        const float2 v1 =
            *(const float2*)&sF[ic * 1156 + (2 * py + iy) * 34 + 2 * px + 2];
        r[iy][0] = v0.x; r[iy][1] = v0.y; r[iy][2] = v1.x; r[iy][3] = v1.y;
      }
#pragma unroll
      for (int o = 0; o < 8; ++o) {
        const float* w = &sW2[(oh * 8 + o) * 72 + ic * 9];
        double w9[9];
#pragma unroll
        for (int k = 0; k < 9; ++k) w9[k] = (double)w[k];
#pragma unroll
        for (int dy = 0; dy < 2; ++dy)
#pragma unroll
          for (int dx = 0; dx < 2; ++dx) {
            double s = acc[o][dy * 2 + dx];
#pragma unroll
            for (int ky = 0; ky < 3; ++ky)
#pragma unroll
              for (int kx = 0; kx < 3; ++kx)
                s = fma((double)r[dy + ky][dx + kx], w9[ky * 3 + kx], s);
            acc[o][dy * 2 + dx] = s;
          }
      }
    }
#pragma unroll
    for (int o = 0; o < 8; ++o) {
      const int oc = oh * 8 + o;
      const double best =
          fmax(fmax(acc[o][0], acc[o][1]), fmax(acc[o][2], acc[o][3]));
      ob[oc * 256] = (float)fmax(best + (double)sB2[oc], 0.0);
    }
  }
}

// ---------------------------------------------------------------------------
// Fallback fused conv (small-ws path, R2/R3-proven)
// ---------------------------------------------------------------------------
__global__ __launch_bounds__(256) void conv_fused(
    const float* __restrict__ x,
    const float* __restrict__ cw1, const float* __restrict__ cb1,
    const float* __restrict__ cw2, const float* __restrict__ cb2,
    float* __restrict__ flat) {
  __shared__ float sX[66 * 66];
  __shared__ float sF[8 * 34 * 34];
  __shared__ float sW1[72];
  __shared__ float sW2[1152];
  __shared__ float sB1[8];
  __shared__ float sB2[16];

  const int b = blockIdx.x;
  const int t = threadIdx.x;

  for (int i = t; i < 66 * 66; i += 256) sX[i] = 0.0f;
  for (int i = t; i < 8 * 34 * 34; i += 256) sF[i] = 0.0f;
  if (t < 72) sW1[t] = cw1[t];
  for (int i = t; i < 1152; i += 256) sW2[i] = cw2[i];
  if (t < 8)  sB1[t] = cb1[t];
  if (t < 16) sB2[t] = cb2[t];
  __syncthreads();

  const float* xb = x + (size_t)b * 4096;
  for (int i = t; i < 4096; i += 256)
    sX[((i >> 6) + 1) * 66 + (i & 63) + 1] = xb[i];
  __syncthreads();

  for (int p = t; p < 8192; p += 256) {
    const int ch = p >> 10, pos = p & 1023;
    const int py1 = pos >> 5, px1 = pos & 31;
    double best = -1e300;
#pragma unroll
    for (int dy = 0; dy < 2; ++dy)
#pragma unroll
      for (int dx = 0; dx < 2; ++dx) {
        const int y = 2 * py1 + dy, xx = 2 * px1 + dx;
        double s = 0.0;
#pragma unroll
        for (int ky = 0; ky < 3; ++ky)
#pragma unroll
          for (int kx = 0; kx < 3; ++kx)
            s = fma((double)sX[(y + ky) * 66 + xx + kx],
                    (double)sW1[ch * 9 + ky * 3 + kx], s);
        best = fmax(best, s);
      }
    sF[ch * 1156 + (py1 + 1) * 34 + px1 + 1] =
        (float)fmax(best + (double)sB1[ch], 0.0);
  }
  __syncthreads();

  const int py = t >> 4, px = t & 15;
  for (int oh = 0; oh < 2; ++oh) {
    double acc[8][4];
#pragma unroll
    for (int o = 0; o < 8; ++o)
#pragma unroll
      for (int q = 0; q < 4; ++q) acc[o][q] = 0.0;
#pragma unroll
    for (int ic = 0; ic < 8; ++ic) {
      double r[4][4];
#pragma unroll
      for (int iy = 0; iy < 4; ++iy)
#pragma unroll
        for (int ix = 0; ix < 4; ++ix)
          r[iy][ix] = (double)sF[ic * 1156 + (2 * py + iy) * 34 + 2 * px + ix];
#pragma unroll
      for (int o = 0; o < 8; ++o) {
        const float* w = &sW2[(oh * 8 + o) * 72 + ic * 9];
        double w9[9];
#pragma unroll
        for (int k = 0; k < 9; ++k) w9[k] = (double)w[k];
#pragma unroll
        for (int dy = 0; dy < 2; ++dy)
#pragma unroll
          for (int dx = 0; dx < 2; ++dx) {
            double s = acc[o][dy * 2 + dx];
#pragma unroll
            for (int ky = 0; ky < 3; ++ky)
#pragma unroll
              for (int kx = 0; kx < 3; ++kx)
                s = fma(r[dy + ky][dx + kx], w9[ky * 3 + kx], s);
            acc[o][dy * 2 + dx] = s;
          }
      }
    }
    float* ob = flat + (size_t)b * 4096 + py * 16 + px;
#pragma unroll
    for (int o = 0; o < 8; ++o) {
      const int oc = oh * 8 + o;
      double best =
          fmax(fmax(acc[o][0], acc[o][1]), fmax(acc[o][2], acc[o][3]));
      ob[oc * 256] = (float)fmax(best + (double)sB2[oc], 0.0);
    }
  }
}

// ---------------------------------------------------------------------------
// f64 MFMA split-K GEMM (R9-proven): used for GEMM2 and as GEMM1 fallback.
// ---------------------------------------------------------------------------
__global__ __launch_bounds__(256, 2) void gemm_mfma_128(
    const float* __restrict__ A, const float* __restrict__ B,
    double* __restrict__ P, int M, int N, int K, int Kc) {
  __shared__ double As[16][131];
  __shared__ double Bs[16][131];

  const int t = threadIdx.x;
  const int n0 = blockIdx.x * 128;
  const int m0 = blockIdx.y * 128;
  const int s  = blockIdx.z;
  const int kb = s * Kc;
  const int rS = t >> 2;
  const int cS = (t & 3) * 4;
  const int w  = t >> 6;
  const int lane = t & 63;
  const int lq = lane >> 4;
  const int ln = lane & 15;
  const int mW = (w >> 1) * 64;
  const int nW = (w & 1) * 64;

  f64x4 acc[4][4];
#pragma unroll
  for (int g = 0; g < 4; ++g)
#pragma unroll
    for (int h = 0; h < 4; ++h) acc[g][h] = {0.0, 0.0, 0.0, 0.0};

  const float* Alo = &A[(size_t)(m0 + rS) * K + cS];
  const float* Ahi = &A[(size_t)(m0 + 64 + rS) * K + cS];
  const float* Blo = &B[(size_t)(n0 + rS) * K + cS];
  const float* Bhi = &B[(size_t)(n0 + 64 + rS) * K + cS];

  float4 a0 = *(const float4*)&Alo[kb];
  float4 a1 = *(const float4*)&Ahi[kb];
  float4 b0 = *(const float4*)&Blo[kb];
  float4 b1 = *(const float4*)&Bhi[kb];

  for (int k0 = kb; k0 < kb + Kc; k0 += 16) {
    __syncthreads();
    As[cS + 0][rS] = (double)a0.x; As[cS + 1][rS] = (double)a0.y;
    As[cS + 2][rS] = (double)a0.z; As[cS + 3][rS] = (double)a0.w;
    As[cS + 0][64 + rS] = (double)a1.x; As[cS + 1][64 + rS] = (double)a1.y;
    As[cS + 2][64 + rS] = (double)a1.z; As[cS + 3][64 + rS] = (double)a1.w;
    Bs[cS + 0][rS] = (double)b0.x; Bs[cS + 1][rS] = (double)b0.y;
    Bs[cS + 2][rS] = (double)b0.z; Bs[cS + 3][rS] = (double)b0.w;
    Bs[cS + 0][64 + rS] = (double)b1.x; Bs[cS + 1][64 + rS] = (double)b1.y;
    Bs[cS + 2][64 + rS] = (double)b1.z; Bs[cS + 3][64 + rS] = (double)b1.w;
    if (k0 + 16 < kb + Kc) {
      a0 = *(const float4*)&Alo[k0 + 16];
      a1 = *(const float4*)&Ahi[k0 + 16];
      b0 = *(const float4*)&Blo[k0 + 16];
      b1 = *(const float4*)&Bhi[k0 + 16];
    }
    __syncthreads();
#pragma unroll
    for (int kq = 0; kq < 4; ++kq) {
      const int kr = 4 * kq + lq;
      double aF[4], bF[4];
#pragma unroll
      for (int g = 0; g < 4; ++g) aF[g] = As[kr][mW + 16 * g + ln];
#pragma unroll
      for (int h = 0; h < 4; ++h) bF[h] = Bs[kr][nW + 16 * h + ln];
#pragma unroll
      for (int g = 0; g < 4; ++g)
#pragma unroll
        for (int h = 0; h < 4; ++h)
          acc[g][h] = __builtin_amdgcn_mfma_f64_16x16x4f64(aF[g], bF[h],
                                                           acc[g][h], 0, 0, 0);
    }
  }

  double* Pp = P + (size_t)s * M * N;
#pragma unroll
  for (int g = 0; g < 4; ++g) {
#pragma unroll
    for (int h = 0; h < 4; ++h) {
#pragma unroll
      for (int v = 0; v < 4; ++v) {
        const int row = m0 + mW + 16 * g + 4 * lq + v;
        const int col = n0 + nW + 16 * h + ln;
        Pp[(size_t)row * N + col] = acc[g][h][v];
      }
    }
  }
}

// ---------------------------------------------------------------------------
// Ozaki prep: per row, exact pow2 scale + 31-bit quantize + 4x int8 slices.
// rows 0..1023 = A (flat), 1024..2047 = B (w1).
// planes: [mat*4+slice][1024][4096] int8; scales[r] = 2^(e-30) f64.
// ---------------------------------------------------------------------------
__global__ __launch_bounds__(256) void ozaki_prep(
    const float* __restrict__ A, const float* __restrict__ B,
    signed char* __restrict__ planes, double* __restrict__ scales) {
  const int r = blockIdx.x;
  const int mat = r >> 10;
  const int row = r & 1023;
  const float* src = (mat ? B : A) + (size_t)row * 4096;
  const int t = threadIdx.x;

  float mx = 0.0f;
  for (int k = t; k < 4096; k += 256) mx = fmaxf(mx, fabsf(src[k]));
#pragma unroll
  for (int o = 32; o > 0; o >>= 1) mx = fmaxf(mx, __shfl_down(mx, o));
  __shared__ float red[4];
  if ((t & 63) == 0) red[t >> 6] = mx;
  __syncthreads();
  mx = fmaxf(fmaxf(red[0], red[1]), fmaxf(red[2], red[3]));

  const int e = (mx > 0.0f) ? (ilogbf(mx) + 1) : 0;
  const double qs = ldexp(1.0, 30 - e);  // |a|*qs < 2^30 (strict)
  if (t == 0) scales[r] = ldexp(1.0, e - 30);

  signed char* p0 = planes + (size_t)(mat * 4) * 4194304 + (size_t)row * 4096;
  for (int k = t; k < 4096; k += 256) {
    const int q = (int)lrint((double)src[k] * qs);
    const int q1 = (q + (1 << 23)) >> 24;  const int r1 = q - (q1 << 24);
    const int q2 = (r1 + (1 << 16)) >> 17; const int r2 = r1 - (q2 << 17);
    const int q3 = (r2 + (1 << 9)) >> 10;  const int r3 = r2 - (q3 << 10);
    const int q4 = (r3 + (1 << 2)) >> 3;
    p0[k] = (signed char)q1;
    p0[4194304 + k] = (signed char)q2;
    p0[2 * 4194304 + k] = (signed char)q3;
    p0[3 * 4194304 + k] = (signed char)q4;
  }
}

#if HAVE_I8_MFMA
// ---------------------------------------------------------------------------
// GEMM1 via i8 MFMA: 64x64 block tile, 4 waves x 32x32, BK=64.
// 13 slice-pair passes in 5 exact-i32 weight groups (2^48/41/34/27/20).
// Fused f64 combine + f32-grid tanh epilogue -> h1 directly (no partials).
// ---------------------------------------------------------------------------
__global__ __launch_bounds__(256, 1) void gemm1_i8(
    const signed char* __restrict__ planes, const double* __restrict__ scales,
    const float* __restrict__ bias, float* __restrict__ h1) {
  __shared__ signed char sA[4][64][80];  // 20.0 KB (80 = 64+16 pad, 16B-aligned rows)
  __shared__ signed char sB[4][64][80];  // 20.0 KB

  const int t = threadIdx.x;
  const int n0 = blockIdx.x * 64;
  const int m0 = blockIdx.y * 64;
  const int w = t >> 6;
  const int lane = t & 63;
  const int lq = lane >> 4;
  const int ln = lane & 15;
  const int mW = (w >> 1) * 32;
  const int nW = (w & 1) * 32;
  const int rowS = t >> 2;        // staging row 0..63
  const int kS = (t & 3) * 16;    // staging k offset 0,16,32,48

  v4i acc[4][5];                  // [pos g*2+h][weight group]
#pragma unroll
  for (int p = 0; p < 4; ++p)
#pragma unroll
    for (int g = 0; g < 5; ++g) acc[p][g] = (v4i){0, 0, 0, 0};

  const signed char* pA = planes;
  const signed char* pB = planes + 4ull * 4194304;

  v4i pa[4], pb[4];
#pragma unroll
  for (int sl = 0; sl < 4; ++sl) {
    pa[sl] = *(const v4i*)(pA + (size_t)sl * 4194304 +
                           (size_t)(m0 + rowS) * 4096 + kS);
    pb[sl] = *(const v4i*)(pB + (size_t)sl * 4194304 +
                           (size_t)(n0 + rowS) * 4096 + kS);
  }

  for (int k0 = 0; k0 < 4096; k0 += 64) {
    __syncthreads();  // previous iteration's LDS reads done
#pragma unroll
    for (int sl = 0; sl < 4; ++sl) {
      *(v4i*)&sA[sl][rowS][kS] = pa[sl];
      *(v4i*)&sB[sl][rowS][kS] = pb[sl];
    }
    if (k0 + 64 < 4096) {
#pragma unroll
      for (int sl = 0; sl < 4; ++sl) {
        pa[sl] = *(const v4i*)(pA + (size_t)sl * 4194304 +
                               (size_t)(m0 + rowS) * 4096 + k0 + 64 + kS);
        pb[sl] = *(const v4i*)(pB + (size_t)sl * 4194304 +
                               (size_t)(n0 + rowS) * 4096 + k0 + 64 + kS);
      }
    }
    __syncthreads();  // writes visible

    v4i aF[2][4], bF[2][4];
#pragma unroll
    for (int g = 0; g < 2; ++g)
#pragma unroll
      for (int sl = 0; sl < 4; ++sl)
        aF[g][sl] = *(const v4i*)&sA[sl][mW + 16 * g + ln][lq * 16];
#pragma unroll
    for (int h = 0; h < 2; ++h)
#pragma unroll
      for (int sl = 0; sl < 4; ++sl)
        bF[h][sl] = *(const v4i*)&sB[sl][nW + 16 * h + ln][lq * 16];

#pragma unroll
    for (int g = 0; g < 2; ++g) {
#pragma unroll
      for (int h = 0; h < 2; ++h) {
        const int p = g * 2 + h;
        // group 2^48: (0,0)
        acc[p][0] = __builtin_amdgcn_mfma_i32_16x16x64_i8(
            aF[g][0], bF[h][0], acc[p][0], 0, 0, 0);
        // group 2^41: (0,1)+(1,0)
        acc[p][1] = __builtin_amdgcn_mfma_i32_16x16x64_i8(
            aF[g][0], bF[h][1], acc[p][1], 0, 0, 0);
        acc[p][1] = __builtin_amdgcn_mfma_i32_16x16x64_i8(
            aF[g][1], bF[h][0], acc[p][1], 0, 0, 0);
        // group 2^34: (0,2)+(1,1)+(2,0)
        acc[p][2] = __builtin_amdgcn_mfma_i32_16x16x64_i8(
            aF[g][0], bF[h][2], acc[p][2], 0, 0, 0);
        acc[p][2] = __builtin_amdgcn_mfma_i32_16x16x64_i8(
            aF[g][1], bF[h][1], acc[p][2], 0, 0, 0);
        acc[p][2] = __builtin_amdgcn_mfma_i32_16x16x64_i8(
            aF[g][2], bF[h][0], acc[p][2], 0, 0, 0);
        // group 2^27: (0,3)+(1,2)+(2,1)+(3,0)
        acc[p][3] = __builtin_amdgcn_mfma_i32_16x16x64_i8(
            aF[g][0], bF[h][3], acc[p][3], 0, 0, 0);
        acc[p][3] = __builtin_amdgcn_mfma_i32_16x16x64_i8(
            aF[g][1], bF[h][2], acc[p][3], 0, 0, 0);
        acc[p][3] = __builtin_amdgcn_mfma_i32_16x16x64_i8(
            aF[g][2], bF[h][1], acc[p][3], 0, 0, 0);
        acc[p][3] = __builtin_amdgcn_mfma_i32_16x16x64_i8(
            aF[g][3], bF[h][0], acc[p][3], 0, 0, 0);
        // group 2^20: (1,3)+(2,2)+(3,1)
        acc[p][4] = __builtin_amdgcn_mfma_i32_16x16x64_i8(
            aF[g][1], bF[h][3], acc[p][4], 0, 0, 0);
        acc[p][4] = __builtin_amdgcn_mfma_i32_16x16x64_i8(
            aF[g][2], bF[h][2], acc[p][4], 0, 0, 0);
        acc[p][4] = __builtin_amdgcn_mfma_i32_16x16x64_i8(
            aF[g][3], bF[h][1], acc[p][4], 0, 0, 0);
      }
    }
  }

#pragma unroll
  for (int g = 0; g < 2; ++g) {
#pragma unroll
    for (int h = 0; h < 2; ++h) {
      const int p = g * 2 + h;
#pragma unroll
      for (int v = 0; v < 4; ++v) {
        const int row = m0 + mW + 16 * g + 4 * lq + v;
        const int col = n0 + nW + 16 * h + ln;
        const double sum = scales[row] * scales[1024 + col] *
            ((double)acc[p][0][v] * 0x1p48 + (double)acc[p][1][v] * 0x1p41 +
             (double)acc[p][2][v] * 0x1p34 + (double)acc[p][3][v] * 0x1p27 +
             (double)acc[p][4][v] * 0x1p20);
        const float zg = (float)sum;               // f32 matmul-output grid
        const float z = zg + bias[col];            // f32 bias add
        h1[(size_t)row * 1024 + col] = (float)tanh((double)z);
      }
    }
  }
}
#endif  // HAVE_I8_MFMA

// ---------------------------------------------------------------------------
// Reduce S f64 partials + tanh epilogue (fallback GEMM1 path).
// ---------------------------------------------------------------------------
__global__ __launch_bounds__(256) void reduce_tanh(
    const double* __restrict__ P, int S, const float* __restrict__ bias,
    float* __restrict__ C, int N, int total) {
  const int idx = blockIdx.x * 256 + threadIdx.x;
  if (idx >= total) return;
  double sum = 0.0;
  for (int s = 0; s < S; ++s) sum += P[(size_t)s * total + idx];
  const float zg = (float)sum;
  const float z = zg + bias[idx & (N - 1)];
  C[idx] = (float)tanh((double)z);
}

// ---------------------------------------------------------------------------
// GEMM2 reduce + tanh + row-L2-normalize, fused (R6/R9-proven).
// ---------------------------------------------------------------------------
__global__ __launch_bounds__(256) void reduce_tanh_norm(
    const double* __restrict__ P, int S, const float* __restrict__ bias,
    float* __restrict__ last, float* __restrict__ nrm) {
  const int b = blockIdx.x;
  const int t = threadIdx.x;
  const int idx = b * 256 + t;
  const int total = 1024 * 256;
  double sum = 0.0;
  for (int s = 0; s < S; ++s) sum += P[(size_t)s * total + idx];
  const float zg = (float)sum;
  const float z = zg + bias[t];
  const float v = (float)tanh((double)z);
  last[idx] = v;

  const float sq = v * v;
  double s = (double)sq;
#pragma unroll
  for (int o = 32; o > 0; o >>= 1) s += __shfl_down(s, o);
  __shared__ double red[4];
  if ((t & 63) == 0) red[t >> 6] = s;
  __syncthreads();
  const double totalSq = red[0] + red[1] + red[2] + red[3];
  const float s32 = (float)totalSq;
  const float den = sqrtf(s32) + 1e-12f;
  nrm[idx] = v / den;
}

// ---------------------------------------------------------------------------
// Gram + threshold adjacency (R6/R9-proven VALU kernel).
// ---------------------------------------------------------------------------
__global__ __launch_bounds__(256) void gram_adj_direct(
    const float* __restrict__ Nrm, float* __restrict__ adj, int Msz, int K) {
  __shared__ double As[16][66];
  __shared__ double Bs[16][66];

  const int t = threadIdx.x;
  const int n0 = blockIdx.x * 64;
  const int m0 = blockIdx.y * 64;
  const int lm = t >> 2;
  const int lk4 = (t & 3) * 4;
  const int ty = t >> 4;
  const int tx = t & 15;

  double acc[4][4];
#pragma unroll
  for (int i = 0; i < 4; ++i)
#pragma unroll
    for (int j = 0; j < 4; ++j) acc[i][j] = 0.0;

  for (int k0 = 0; k0 < K; k0 += 16) {
    const float4 av = *(const float4*)&Nrm[(size_t)(m0 + lm) * K + k0 + lk4];
    const float4 bv = *(const float4*)&Nrm[(size_t)(n0 + lm) * K + k0 + lk4];
    __syncthreads();
    As[lk4 + 0][lm] = (double)av.x; As[lk4 + 1][lm] = (double)av.y;
    As[lk4 + 2][lm] = (double)av.z; As[lk4 + 3][lm] = (double)av.w;
    Bs[lk4 + 0][lm] = (double)bv.x; Bs[lk4 + 1][lm] = (double)bv.y;
    Bs[lk4 + 2][lm] = (double)bv.z; Bs[lk4 + 3][lm] = (double)bv.w;
    __syncthreads();
#pragma unroll
    for (int k = 0; k < 16; ++k) {
      const double2 a01 = *(const double2*)&As[k][2 * ty];
      const double2 a23 = *(const double2*)&As[k][32 + 2 * ty];
      const double2 b01 = *(const double2*)&Bs[k][2 * tx];
      const double2 b23 = *(const double2*)&Bs[k][32 + 2 * tx];
      const double ar[4] = {a01.x, a01.y, a23.x, a23.y};
      const double br[4] = {b01.x, b01.y, b23.x, b23.y};
#pragma unroll
      for (int i = 0; i < 4; ++i)
#pragma unroll
        for (int j = 0; j < 4; ++j)
          acc[i][j] = fma(ar[i], br[j], acc[i][j]);
    }
  }

  const int rows[4] = {m0 + 2 * ty, m0 + 2 * ty + 1,
                       m0 + 32 + 2 * ty, m0 + 32 + 2 * ty + 1};
  const int cols[4] = {n0 + 2 * tx, n0 + 2 * tx + 1,
                       n0 + 32 + 2 * tx, n0 + 32 + 2 * tx + 1};
#pragma unroll
  for (int i = 0; i < 4; ++i)
#pragma unroll
    for (int j = 0; j < 4; ++j) {
      const float g = (float)acc[i][j];
      const float fid = g * g;
      float v = (fid >= 0.8f) ? 1.0f : ((fid >= 0.6f) ? 0.5f : 0.0f);
      if (rows[i] == cols[j]) v = 0.0f;
      adj[(size_t)rows[i] * Msz + cols[j]] = v;
    }
}

// ---------------------------------------------------------------------------
// BatchNorm1d training mode (proven).
// ---------------------------------------------------------------------------
__global__ __launch_bounds__(256) void bn_stats(
    const float* __restrict__ last, const float* __restrict__ gamma,
    const float* __restrict__ beta, float* __restrict__ out) {
  const int j = blockIdx.x;
  const int t = threadIdx.x;
  double v[4];
  double s = 0.0;
#pragma unroll
  for (int i = 0; i < 4; ++i) {
    v[i] = (double)last[(size_t)(i * 256 + t) * 256 + j];
    s += v[i];
  }
#pragma unroll
  for (int o = 32; o > 0; o >>= 1) s += __shfl_down(s, o);
  __shared__ double red[4];
  if ((t & 63) == 0) red[t >> 6] = s;
  __syncthreads();
  const double mean = (red[0] + red[1] + red[2] + red[3]) * (1.0 / 1024.0);
  double q = 0.0;
#pragma unroll
  for (int i = 0; i < 4; ++i) {
    const double d = v[i] - mean;
    q += d * d;
  }
#pragma unroll
  for (int o = 32; o > 0; o >>= 1) q += __shfl_down(q, o);
  __syncthreads();
  if ((t & 63) == 0) red[t >> 6] = q;
  __syncthreads();
  const double var = (red[0] + red[1] + red[2] + red[3]) * (1.0 / 1024.0);
  const double g = (double)gamma[j] / sqrt(var + 1e-5);
  const double be = (double)beta[j];
#pragma unroll
  for (int i = 0; i < 4; ++i)
    out[(size_t)(i * 256 + t) * 256 + j] = (float)((v[i] - mean) * g + be);
}

// ---------------------------------------------------------------------------
extern "C" void kernel_launch(void* const* d_in, const int* in_sizes, int n_in,
                              void* d_out, int out_size, void* d_ws,
                              size_t ws_size, hipStream_t stream) {
  const float* x     = (const float*)d_in[0];
  const float* cw1   = (const float*)d_in[1];
  const float* cb1   = (const float*)d_in[2];
  const float* cw2   = (const float*)d_in[3];
  const float* cb2   = (const float*)d_in[4];
  const float* w1    = (const float*)d_in[5];   // [1024,4096]
  const float* b1    = (const float*)d_in[6];
  const float* w2    = (const float*)d_in[7];   // [256,1024]
  const float* b2    = (const float*)d_in[8];
  const float* gamma = (const float*)d_in[9];
  const float* beta  = (const float*)d_in[10];

  float* outp = (float*)d_out;            // [1024,256]
  float* adj  = outp + 1024 * 256;        // [1024,1024]

  float* ws    = (float*)d_ws;
  float* flat  = ws;                      // [1024,4096] @0        16.78 MB
  float* h1    = ws + 4194304;            // [1024,1024]            4.19 MB
  float* last  = ws + 5242880;            // [1024,256]             1.05 MB
  float* nrm   = ws + 5505024;            // [1024,256]             1.05 MB
  double* scal = (double*)(ws + 5767168); // [2048] f64            16 KB
  // shared region (sequential lifetimes): feat1 -> i8 planes -> gemm2 partials
  float* region = ws + 5771264;           // 33.55 MB
  float* feat1 = region;
  signed char* planes = (signed char*)region;
  double* part = (double*)region;
  // total: 5771264*4 + 33554432 = 56,639,488 B

  const size_t needB = 5771264ull * 4ull + 33554432ull;
  const bool full = (ws_size >= needB);

  if (full) {
    conv1_kernel<<<1024, 256, 0, stream>>>(x, cw1, cb1, feat1);
    conv2_kernel<<<1024, 256, 0, stream>>>(feat1, cw2, cb2, flat);
  } else {
    conv_fused<<<1024, 256, 0, stream>>>(x, cw1, cb1, cw2, cb2, flat);
  }

#if HAVE_I8_MFMA
  const bool use_i8 = full;
#else
  const bool use_i8 = false;
#endif

  if (use_i8) {
#if HAVE_I8_MFMA
    // h1 = tanh(flat @ w1^T + b1) via exact int8 Ozaki GEMM (fused epilogue)
    ozaki_prep<<<2048, 256, 0, stream>>>(flat, w1, planes, scal);
    gemm1_i8<<<dim3(16, 16), 256, 0, stream>>>(planes, scal, b1, h1);
#endif
  } else {
    // fallback: f64 MFMA split-K + reduce (R9 path); needs part region
    const int S1 = full ? 8 : 2;
    gemm_mfma_128<<<dim3(8, 8, S1), 256, 0, stream>>>(
        flat, w1, part, 1024, 1024, 4096, 4096 / S1);
    reduce_tanh<<<4096, 256, 0, stream>>>(part, S1, b1, h1, 1024, 1024 * 1024);
  }

  // last = tanh(h1 @ w2^T + b2), then rownorm (f64 MFMA, R9-proven)
  const int S2 = full ? 16 : 4;
  gemm_mfma_128<<<dim3(2, 8, S2), 256, 0, stream>>>(
      h1, w2, part, 1024, 256, 1024, 1024 / S2);
  reduce_tanh_norm<<<1024, 256, 0, stream>>>(part, S2, b2, last, nrm);

  // adj = thr((nrm @ nrm^T)^2), zero diag (proven VALU kernel)
  gram_adj_direct<<<dim3(16, 16), 256, 0, stream>>>(nrm, adj, 1024, 256);

  bn_stats<<<256, 256, 0, stream>>>(last, gamma, beta, outp);
}